// Round 1
// baseline (24490.511 us; speedup 1.0000x reference)
//
#include <hip/hip_runtime.h>

#define HEADS 8
#define HID 16            // per-head channels in both convs (HID == NUM_CLASSES == 16)
#define FDIM 128          // HEADS*HID = feature width of both conv layers
#define NCLS 16
#define NEG_SLOPE 0.2f

// ---------------- float <-> ordered-uint key (for atomicMax on float) ----------
__device__ __forceinline__ unsigned fkey(float f) {
    unsigned u = __float_as_uint(f);
    return (u & 0x80000000u) ? ~u : (u | 0x80000000u);
}
__device__ __forceinline__ float finv(unsigned k) {
    unsigned u = (k & 0x80000000u) ? (k & 0x7fffffffu) : ~k;
    return __uint_as_float(u);
}

// ---------------- GEMM: Y[n,128] = X[n,128] @ W[128,128] -----------------------
// 64-node tile in LDS, 256 threads, each thread 8 nodes x 4 cols.
__global__ __launch_bounds__(256) void gemm128(const float* __restrict__ X,
                                               const float* __restrict__ W,
                                               float* __restrict__ Y, int n) {
    __shared__ float xs[64 * 128];   // 32 KB
    const int t = threadIdx.x;
    const int nb = blockIdx.x * 64;
    {
        const float4* Xv = (const float4*)(X + (size_t)nb * 128);
        float4* sv = (float4*)xs;
        for (int i = t; i < 64 * 32; i += 256) {
            int node = i >> 5;
            float4 v = make_float4(0.f, 0.f, 0.f, 0.f);
            if (nb + node < n) v = Xv[i];
            sv[i] = v;
        }
    }
    __syncthreads();
    const int colb = (t & 31) * 4;
    const int nodeb = (t >> 5) * 8;
    float acc[8][4];
#pragma unroll
    for (int i = 0; i < 8; i++) { acc[i][0] = acc[i][1] = acc[i][2] = acc[i][3] = 0.f; }

    for (int k4 = 0; k4 < 128; k4 += 4) {
        float4 w0 = *(const float4*)(W + (k4 + 0) * 128 + colb);
        float4 w1 = *(const float4*)(W + (k4 + 1) * 128 + colb);
        float4 w2 = *(const float4*)(W + (k4 + 2) * 128 + colb);
        float4 w3 = *(const float4*)(W + (k4 + 3) * 128 + colb);
#pragma unroll
        for (int i = 0; i < 8; i++) {
            float4 xv = *(const float4*)&xs[(nodeb + i) * 128 + k4];
            acc[i][0] += xv.x * w0.x + xv.y * w1.x + xv.z * w2.x + xv.w * w3.x;
            acc[i][1] += xv.x * w0.y + xv.y * w1.y + xv.z * w2.y + xv.w * w3.y;
            acc[i][2] += xv.x * w0.z + xv.y * w1.z + xv.z * w2.z + xv.w * w3.z;
            acc[i][3] += xv.x * w0.w + xv.y * w1.w + xv.z * w2.w + xv.w * w3.w;
        }
    }
#pragma unroll
    for (int i = 0; i < 8; i++) {
        int node = nb + nodeb + i;
        if (node < n)
            *(float4*)(Y + (size_t)node * 128 + colb) =
                make_float4(acc[i][0], acc[i][1], acc[i][2], acc[i][3]);
    }
}

// ---------------- edge pass 1: logits + per-(dst,head) max ---------------------
// thread per (edge, head). logits may be null (then only max is computed).
__global__ __launch_bounds__(256) void edge_logits(const float* __restrict__ xl,
                                                   const float* __restrict__ xr,
                                                   const float* __restrict__ att,
                                                   const int* __restrict__ srcs,
                                                   const int* __restrict__ dsts,
                                                   int E0, int Etot,
                                                   float* __restrict__ logits,
                                                   unsigned* __restrict__ mkey) {
    __shared__ float atts[HEADS * HID];
    const int t = threadIdx.x;
    if (t < HEADS * HID) atts[t] = att[t];
    __syncthreads();
    int gid = blockIdx.x * 256 + t;
    if (gid >= Etot * 8) return;
    const int e = gid >> 3, h = gid & 7;
    int sN, dN;
    if (e < E0) { sN = srcs[e]; dN = dsts[e]; } else { sN = e - E0; dN = sN; }

    const float4* lv = (const float4*)(xl + (size_t)sN * FDIM + h * HID);
    const float4* rv = (const float4*)(xr + (size_t)dN * FDIM + h * HID);
    float acc = 0.f;
#pragma unroll
    for (int c4 = 0; c4 < 4; c4++) {
        float4 l = lv[c4], r = rv[c4];
        float4 a4 = *(const float4*)&atts[h * HID + c4 * 4];
        float v;
        v = l.x + r.x; v = v > 0.f ? v : NEG_SLOPE * v; acc += v * a4.x;
        v = l.y + r.y; v = v > 0.f ? v : NEG_SLOPE * v; acc += v * a4.y;
        v = l.z + r.z; v = v > 0.f ? v : NEG_SLOPE * v; acc += v * a4.z;
        v = l.w + r.w; v = v > 0.f ? v : NEG_SLOPE * v; acc += v * a4.w;
    }
    if (logits) logits[gid] = acc;
    atomicMax(&mkey[dN * 8 + h], fkey(acc));
}

// ---------------- edge pass 2: exp, denom, unnormalized aggregation ------------
__global__ __launch_bounds__(256) void edge_aggregate(const float* __restrict__ xl,
                                                      const float* __restrict__ xr,
                                                      const float* __restrict__ att,
                                                      const float* __restrict__ logits,
                                                      const unsigned* __restrict__ mkey,
                                                      const int* __restrict__ srcs,
                                                      const int* __restrict__ dsts,
                                                      int E0, int Etot,
                                                      float* __restrict__ ssum,
                                                      float* __restrict__ accum) {
    __shared__ float atts[HEADS * HID];
    const int t = threadIdx.x;
    if (t < HEADS * HID) atts[t] = att[t];
    __syncthreads();
    int gid = blockIdx.x * 256 + t;
    if (gid >= Etot * 8) return;
    const int e = gid >> 3, h = gid & 7;
    int sN, dN;
    if (e < E0) { sN = srcs[e]; dN = dsts[e]; } else { sN = e - E0; dN = sN; }

    const float4* lv = (const float4*)(xl + (size_t)sN * FDIM + h * HID);
    float4 l0 = lv[0], l1 = lv[1], l2 = lv[2], l3 = lv[3];

    float logit;
    if (logits) {
        logit = logits[gid];
    } else {
        const float4* rv = (const float4*)(xr + (size_t)dN * FDIM + h * HID);
        float acc = 0.f;
        float4 r0 = rv[0], r1 = rv[1], r2 = rv[2], r3 = rv[3];
        const float4 a0 = *(const float4*)&atts[h * HID + 0];
        const float4 a1 = *(const float4*)&atts[h * HID + 4];
        const float4 a2 = *(const float4*)&atts[h * HID + 8];
        const float4 a3 = *(const float4*)&atts[h * HID + 12];
        float v;
        v = l0.x + r0.x; v = v > 0.f ? v : NEG_SLOPE * v; acc += v * a0.x;
        v = l0.y + r0.y; v = v > 0.f ? v : NEG_SLOPE * v; acc += v * a0.y;
        v = l0.z + r0.z; v = v > 0.f ? v : NEG_SLOPE * v; acc += v * a0.z;
        v = l0.w + r0.w; v = v > 0.f ? v : NEG_SLOPE * v; acc += v * a0.w;
        v = l1.x + r1.x; v = v > 0.f ? v : NEG_SLOPE * v; acc += v * a1.x;
        v = l1.y + r1.y; v = v > 0.f ? v : NEG_SLOPE * v; acc += v * a1.y;
        v = l1.z + r1.z; v = v > 0.f ? v : NEG_SLOPE * v; acc += v * a1.z;
        v = l1.w + r1.w; v = v > 0.f ? v : NEG_SLOPE * v; acc += v * a1.w;
        v = l2.x + r2.x; v = v > 0.f ? v : NEG_SLOPE * v; acc += v * a2.x;
        v = l2.y + r2.y; v = v > 0.f ? v : NEG_SLOPE * v; acc += v * a2.y;
        v = l2.z + r2.z; v = v > 0.f ? v : NEG_SLOPE * v; acc += v * a2.z;
        v = l2.w + r2.w; v = v > 0.f ? v : NEG_SLOPE * v; acc += v * a2.w;
        v = l3.x + r3.x; v = v > 0.f ? v : NEG_SLOPE * v; acc += v * a3.x;
        v = l3.y + r3.y; v = v > 0.f ? v : NEG_SLOPE * v; acc += v * a3.y;
        v = l3.z + r3.z; v = v > 0.f ? v : NEG_SLOPE * v; acc += v * a3.z;
        v = l3.w + r3.w; v = v > 0.f ? v : NEG_SLOPE * v; acc += v * a3.w;
        logit = acc;
    }

    const float m = finv(mkey[dN * 8 + h]);
    const float a = __expf(logit - m);
    atomicAdd(&ssum[dN * 8 + h], a);
    float* out = accum + (size_t)dN * FDIM + h * HID;
    atomicAdd(out + 0,  a * l0.x);
    atomicAdd(out + 1,  a * l0.y);
    atomicAdd(out + 2,  a * l0.z);
    atomicAdd(out + 3,  a * l0.w);
    atomicAdd(out + 4,  a * l1.x);
    atomicAdd(out + 5,  a * l1.y);
    atomicAdd(out + 6,  a * l1.z);
    atomicAdd(out + 7,  a * l1.w);
    atomicAdd(out + 8,  a * l2.x);
    atomicAdd(out + 9,  a * l2.y);
    atomicAdd(out + 10, a * l2.z);
    atomicAdd(out + 11, a * l2.w);
    atomicAdd(out + 12, a * l3.x);
    atomicAdd(out + 13, a * l3.y);
    atomicAdd(out + 14, a * l3.z);
    atomicAdd(out + 15, a * l3.w);
}

// ---------------- normalize + bias + relu (in place) ---------------------------
__global__ __launch_bounds__(256) void finalize_conv(float* __restrict__ accum,
                                                     const float* __restrict__ ssum,
                                                     const float* __restrict__ bias,
                                                     int n) {
    int gid = blockIdx.x * 256 + threadIdx.x;
    if (gid >= n * FDIM) return;
    const int node = gid >> 7;
    const int col = gid & 127;
    const int h = col >> 4;
    float v = accum[gid] / (ssum[node * 8 + h] + 1e-16f) + bias[col];
    accum[gid] = v > 0.f ? v : 0.f;
}

// ---------------- final linear (128->16) + log_softmax -------------------------
// 16 threads per node (one per class), 16 nodes per 256-thread block.
__global__ __launch_bounds__(256) void final_head(const float* __restrict__ H,
                                                  const float* __restrict__ Wlin,
                                                  const float* __restrict__ blin,
                                                  float* __restrict__ out, int n) {
    __shared__ float Ws[128 * NCLS];   // 8 KB
    const int t = threadIdx.x;
    for (int i = t; i < 128 * NCLS; i += 256) Ws[i] = Wlin[i];
    __syncthreads();
    const int cls = t & 15;
    const int node = blockIdx.x * 16 + (t >> 4);
    if (node >= n) return;
    const float* row = H + (size_t)node * FDIM;
    float acc = blin[cls];
#pragma unroll 4
    for (int k = 0; k < 128; k++) acc += row[k] * Ws[k * NCLS + cls];
    // reduce over the 16-lane class group
    float mx = acc;
#pragma unroll
    for (int off = 8; off > 0; off >>= 1) mx = fmaxf(mx, __shfl_xor(mx, off, 16));
    float ex = __expf(acc - mx);
    float sm = ex;
#pragma unroll
    for (int off = 8; off > 0; off >>= 1) sm += __shfl_xor(sm, off, 16);
    out[(size_t)node * NCLS + cls] = acc - mx - __logf(sm);
}

// ==============================================================================
extern "C" void kernel_launch(void* const* d_in, const int* in_sizes, int n_in,
                              void* d_out, int out_size, void* d_ws, size_t ws_size,
                              hipStream_t stream) {
    const float* x    = (const float*)d_in[0];
    const int*   edge = (const int*)d_in[1];
    const float* Wl1  = (const float*)d_in[2];
    const float* Wr1  = (const float*)d_in[3];
    const float* att1 = (const float*)d_in[4];
    const float* b1   = (const float*)d_in[5];
    const float* Wl2  = (const float*)d_in[6];
    const float* Wr2  = (const float*)d_in[7];
    const float* att2 = (const float*)d_in[8];
    const float* b2   = (const float*)d_in[9];
    const float* Wlin = (const float*)d_in[10];
    const float* blin = (const float*)d_in[11];

    const int N = in_sizes[0] / FDIM;        // 50000
    const int E0 = in_sizes[1] / 2;          // 1600000
    const int Etot = E0 + N;                 // + self loops
    const int* srcs = edge;
    const int* dsts = edge + E0;

    float* A = (float*)d_ws;                 // xl   N*128
    float* B = A + (size_t)N * FDIM;         // xr   N*128
    float* C = B + (size_t)N * FDIM;         // accum / h  N*128
    float* S = C + (size_t)N * FDIM;         // softmax denom N*8
    unsigned* M = (unsigned*)(S + (size_t)N * 8);   // max keys N*8
    float* L = (float*)(M + (size_t)N * 8);  // logits Etot*8 (optional)

    const size_t need_with_L =
        ((size_t)3 * N * FDIM + (size_t)2 * N * 8 + (size_t)Etot * 8) * sizeof(float);
    const bool useL = ws_size >= need_with_L;
    float* Lp = useL ? L : nullptr;

    const int gemm_blocks = (N + 63) / 64;
    const int edge_blocks = (Etot * 8 + 255) / 256;
    const int elem_blocks = (N * FDIM + 255) / 256;

    // ---------------- layer 1 ----------------
    hipMemsetAsync(C, 0, (size_t)N * FDIM * sizeof(float), stream);
    hipMemsetAsync(S, 0, (size_t)N * 8 * sizeof(float), stream);
    hipMemsetAsync(M, 0, (size_t)N * 8 * sizeof(unsigned), stream);
    gemm128<<<gemm_blocks, 256, 0, stream>>>(x, Wl1, A, N);
    gemm128<<<gemm_blocks, 256, 0, stream>>>(x, Wr1, B, N);
    edge_logits<<<edge_blocks, 256, 0, stream>>>(A, B, att1, srcs, dsts, E0, Etot, Lp, M);
    edge_aggregate<<<edge_blocks, 256, 0, stream>>>(A, B, att1, Lp, M, srcs, dsts, E0, Etot, S, C);
    finalize_conv<<<elem_blocks, 256, 0, stream>>>(C, S, b1, N);

    // ---------------- layer 2 ----------------
    gemm128<<<gemm_blocks, 256, 0, stream>>>(C, Wl2, A, N);
    gemm128<<<gemm_blocks, 256, 0, stream>>>(C, Wr2, B, N);
    hipMemsetAsync(C, 0, (size_t)N * FDIM * sizeof(float), stream);
    hipMemsetAsync(S, 0, (size_t)N * 8 * sizeof(float), stream);
    hipMemsetAsync(M, 0, (size_t)N * 8 * sizeof(unsigned), stream);
    edge_logits<<<edge_blocks, 256, 0, stream>>>(A, B, att2, srcs, dsts, E0, Etot, Lp, M);
    edge_aggregate<<<edge_blocks, 256, 0, stream>>>(A, B, att2, Lp, M, srcs, dsts, E0, Etot, S, C);
    finalize_conv<<<elem_blocks, 256, 0, stream>>>(C, S, b2, N);

    // ---------------- head ----------------
    final_head<<<(N + 15) / 16, 256, 0, stream>>>(C, Wlin, blin, (float*)d_out, N);
}

// Round 2
// 930.469 us; speedup vs baseline: 26.3206x; 26.3206x over previous
//
#include <hip/hip_runtime.h>

#define HEADS 8
#define HID 16            // per-head channels in both convs (HID == NUM_CLASSES == 16)
#define FDIM 128          // HEADS*HID = feature width of both conv layers
#define NCLS 16
#define NEG_SLOPE 0.2f

// ---------------- GEMM: Y[n,128] = X[n,128] @ W[128,128] -----------------------
// 64-node tile in LDS, 256 threads, each thread 8 nodes x 4 cols.
__global__ __launch_bounds__(256) void gemm128(const float* __restrict__ X,
                                               const float* __restrict__ W,
                                               float* __restrict__ Y, int n) {
    __shared__ float xs[64 * 128];   // 32 KB
    const int t = threadIdx.x;
    const int nb = blockIdx.x * 64;
    {
        const float4* Xv = (const float4*)(X + (size_t)nb * 128);
        float4* sv = (float4*)xs;
        for (int i = t; i < 64 * 32; i += 256) {
            int node = i >> 5;
            float4 v = make_float4(0.f, 0.f, 0.f, 0.f);
            if (nb + node < n) v = Xv[i];
            sv[i] = v;
        }
    }
    __syncthreads();
    const int colb = (t & 31) * 4;
    const int nodeb = (t >> 5) * 8;
    float acc[8][4];
#pragma unroll
    for (int i = 0; i < 8; i++) { acc[i][0] = acc[i][1] = acc[i][2] = acc[i][3] = 0.f; }

    for (int k4 = 0; k4 < 128; k4 += 4) {
        float4 w0 = *(const float4*)(W + (k4 + 0) * 128 + colb);
        float4 w1 = *(const float4*)(W + (k4 + 1) * 128 + colb);
        float4 w2 = *(const float4*)(W + (k4 + 2) * 128 + colb);
        float4 w3 = *(const float4*)(W + (k4 + 3) * 128 + colb);
#pragma unroll
        for (int i = 0; i < 8; i++) {
            float4 xv = *(const float4*)&xs[(nodeb + i) * 128 + k4];
            acc[i][0] += xv.x * w0.x + xv.y * w1.x + xv.z * w2.x + xv.w * w3.x;
            acc[i][1] += xv.x * w0.y + xv.y * w1.y + xv.z * w2.y + xv.w * w3.y;
            acc[i][2] += xv.x * w0.z + xv.y * w1.z + xv.z * w2.z + xv.w * w3.z;
            acc[i][3] += xv.x * w0.w + xv.y * w1.w + xv.z * w2.w + xv.w * w3.w;
        }
    }
#pragma unroll
    for (int i = 0; i < 8; i++) {
        int node = nb + nodeb + i;
        if (node < n)
            *(float4*)(Y + (size_t)node * 128 + colb) =
                make_float4(acc[i][0], acc[i][1], acc[i][2], acc[i][3]);
    }
}

// ---------------- CSR build ----------------------------------------------------
__global__ __launch_bounds__(256) void set_ones(int* __restrict__ cnt, int n) {
    int i = blockIdx.x * 256 + threadIdx.x;
    if (i < n) cnt[i] = 1;   // self loop
}

__global__ __launch_bounds__(256) void count_edges(const int* __restrict__ dsts,
                                                   int E0, int* __restrict__ cnt) {
    int e = blockIdx.x * 256 + threadIdx.x;
    if (e < E0) atomicAdd(&cnt[dsts[e]], 1);
}

// single-block exclusive scan over n counters; writes off[0..n] and cursor copy
__global__ __launch_bounds__(1024) void exscan(const int* __restrict__ cnt,
                                               int* __restrict__ off,
                                               int* __restrict__ cursor, int n) {
    __shared__ int tmp[1024];
    __shared__ int carry;
    const int t = threadIdx.x;
    if (t == 0) carry = 0;
    __syncthreads();
    for (int base = 0; base < n; base += 1024) {
        int v = (base + t < n) ? cnt[base + t] : 0;
        tmp[t] = v;
        __syncthreads();
        for (int d = 1; d < 1024; d <<= 1) {
            int add = (t >= d) ? tmp[t - d] : 0;
            __syncthreads();
            tmp[t] += add;
            __syncthreads();
        }
        int incl = tmp[t];
        int exc = incl - v + carry;      // reads carry BEFORE update below
        if (base + t < n) { off[base + t] = exc; cursor[base + t] = exc; }
        __syncthreads();
        if (t == 1023) carry += incl;
        __syncthreads();
    }
    if (t == 0) off[n] = carry;
}

// scatter src ids into adjacency; gid in [0,E0) real edges, [E0,E0+n) self loops
__global__ __launch_bounds__(256) void scatter_edges(const int* __restrict__ srcs,
                                                     const int* __restrict__ dsts,
                                                     int E0, int n,
                                                     int* __restrict__ cursor,
                                                     int* __restrict__ adj) {
    int gid = blockIdx.x * 256 + threadIdx.x;
    if (gid >= E0 + n) return;
    int sN, dN;
    if (gid < E0) { sN = srcs[gid]; dN = dsts[gid]; }
    else          { sN = gid - E0;  dN = sN; }
    int pos = atomicAdd(&cursor[dN], 1);
    adj[pos] = sN;
}

// ---------------- fused gather: logits + online softmax + aggregate + bias+relu
// One wave per destination node; lane = head*8 + chanpair. 4 nodes / 256-block.
__global__ __launch_bounds__(256) void node_gather(const float* __restrict__ xl,
                                                   const float* __restrict__ xr,
                                                   const float* __restrict__ att,
                                                   const int* __restrict__ adj,
                                                   const int* __restrict__ off,
                                                   const float* __restrict__ bias,
                                                   float* __restrict__ out, int n) {
    const int t = threadIdx.x;
    const int lane = t & 63;
    const int node = blockIdx.x * 4 + (t >> 6);
    if (node >= n) return;
    const int h = lane >> 3;           // 0..7
    const int col = h * 16 + (lane & 7) * 2;
    const float a0 = att[col], a1 = att[col + 1];
    const float2 r = *(const float2*)(xr + (size_t)node * FDIM + col);
    float mx = -1e30f, s = 0.f, acc0 = 0.f, acc1 = 0.f;
    const int beg = off[node], end = off[node + 1];
    for (int j = beg; j < end; j++) {
        const int src = adj[j];
        const float2 l = *(const float2*)(xl + (size_t)src * FDIM + col);
        float v0 = l.x + r.x; v0 = v0 > 0.f ? v0 : NEG_SLOPE * v0;
        float v1 = l.y + r.y; v1 = v1 > 0.f ? v1 : NEG_SLOPE * v1;
        float p = v0 * a0 + v1 * a1;
        p += __shfl_xor(p, 1, 64);      // all-reduce within the 8-lane head group
        p += __shfl_xor(p, 2, 64);
        p += __shfl_xor(p, 4, 64);
        float nm = fmaxf(mx, p);
        float scale = __expf(mx - nm);
        float a = __expf(p - nm);
        s = s * scale + a;
        acc0 = acc0 * scale + a * l.x;
        acc1 = acc1 * scale + a * l.y;
        mx = nm;
    }
    const float inv = 1.f / (s + 1e-16f);
    float o0 = acc0 * inv + bias[col];
    float o1 = acc1 * inv + bias[col + 1];
    out[(size_t)node * FDIM + col]     = o0 > 0.f ? o0 : 0.f;
    out[(size_t)node * FDIM + col + 1] = o1 > 0.f ? o1 : 0.f;
}

// ---------------- final linear (128->16) + log_softmax -------------------------
__global__ __launch_bounds__(256) void final_head(const float* __restrict__ H,
                                                  const float* __restrict__ Wlin,
                                                  const float* __restrict__ blin,
                                                  float* __restrict__ out, int n) {
    __shared__ float Ws[128 * NCLS];   // 8 KB
    const int t = threadIdx.x;
    for (int i = t; i < 128 * NCLS; i += 256) Ws[i] = Wlin[i];
    __syncthreads();
    const int cls = t & 15;
    const int node = blockIdx.x * 16 + (t >> 4);
    if (node >= n) return;
    const float* row = H + (size_t)node * FDIM;
    float acc = blin[cls];
#pragma unroll 4
    for (int k = 0; k < 128; k++) acc += row[k] * Ws[k * NCLS + cls];
    float mx = acc;
#pragma unroll
    for (int off = 8; off > 0; off >>= 1) mx = fmaxf(mx, __shfl_xor(mx, off, 16));
    float ex = __expf(acc - mx);
    float sm = ex;
#pragma unroll
    for (int off = 8; off > 0; off >>= 1) sm += __shfl_xor(sm, off, 16);
    out[(size_t)node * NCLS + cls] = acc - mx - __logf(sm);
}

// ==============================================================================
extern "C" void kernel_launch(void* const* d_in, const int* in_sizes, int n_in,
                              void* d_out, int out_size, void* d_ws, size_t ws_size,
                              hipStream_t stream) {
    const float* x    = (const float*)d_in[0];
    const int*   edge = (const int*)d_in[1];
    const float* Wl1  = (const float*)d_in[2];
    const float* Wr1  = (const float*)d_in[3];
    const float* att1 = (const float*)d_in[4];
    const float* b1   = (const float*)d_in[5];
    const float* Wl2  = (const float*)d_in[6];
    const float* Wr2  = (const float*)d_in[7];
    const float* att2 = (const float*)d_in[8];
    const float* b2   = (const float*)d_in[9];
    const float* Wlin = (const float*)d_in[10];
    const float* blin = (const float*)d_in[11];

    const int N = in_sizes[0] / FDIM;        // 50000
    const int E0 = in_sizes[1] / 2;          // 1600000
    const int Etot = E0 + N;
    const int* srcs = edge;
    const int* dsts = edge + E0;

    float* A   = (float*)d_ws;               // xl   N*128
    float* B   = A + (size_t)N * FDIM;       // xr   N*128
    float* C   = B + (size_t)N * FDIM;       // conv output N*128
    int* cnt    = (int*)(C + (size_t)N * FDIM);
    int* off    = cnt + N;                   // N+1
    int* cursor = off + N + 1;               // N
    int* adj    = cursor + N;                // Etot

    const int gemm_blocks = (N + 63) / 64;
    const int node_blocks = (N + 3) / 4;

    // ---------------- CSR build (shared by both layers) ----------------
    set_ones<<<(N + 255) / 256, 256, 0, stream>>>(cnt, N);
    count_edges<<<(E0 + 255) / 256, 256, 0, stream>>>(dsts, E0, cnt);
    exscan<<<1, 1024, 0, stream>>>(cnt, off, cursor, N);
    scatter_edges<<<(Etot + 255) / 256, 256, 0, stream>>>(srcs, dsts, E0, N, cursor, adj);

    // ---------------- layer 1 ----------------
    gemm128<<<gemm_blocks, 256, 0, stream>>>(x, Wl1, A, N);
    gemm128<<<gemm_blocks, 256, 0, stream>>>(x, Wr1, B, N);
    node_gather<<<node_blocks, 256, 0, stream>>>(A, B, att1, adj, off, b1, C, N);

    // ---------------- layer 2 ----------------
    gemm128<<<gemm_blocks, 256, 0, stream>>>(C, Wl2, A, N);
    gemm128<<<gemm_blocks, 256, 0, stream>>>(C, Wr2, B, N);
    node_gather<<<node_blocks, 256, 0, stream>>>(A, B, att2, adj, off, b2, C, N);

    // ---------------- head ----------------
    final_head<<<(N + 15) / 16, 256, 0, stream>>>(C, Wlin, blin, (float*)d_out, N);
}

// Round 3
// 648.371 us; speedup vs baseline: 37.7724x; 1.4351x over previous
//
#include <hip/hip_runtime.h>

#define HEADS 8
#define HID 16            // per-head channels in both convs (HID == NUM_CLASSES == 16)
#define FDIM 128          // HEADS*HID = feature width of both conv layers
#define NCLS 16
#define NEG_SLOPE 0.2f

// ---------------- GEMM: Y[n,128] = X[n,128] @ W[128,128], dual-output ----------
// 64-node tile in LDS, 256 threads, each thread 8 nodes x 4 cols.
// blockIdx.y selects (W0->Y0) or (W1->Y1) so both transforms share one launch.
__global__ __launch_bounds__(256) void gemm128_dual(const float* __restrict__ X,
                                                    const float* __restrict__ W0,
                                                    const float* __restrict__ W1,
                                                    float* __restrict__ Y0,
                                                    float* __restrict__ Y1, int n) {
    const float* W = blockIdx.y ? W1 : W0;
    float* Y = blockIdx.y ? Y1 : Y0;
    __shared__ float xs[64 * 128];   // 32 KB
    const int t = threadIdx.x;
    const int nb = blockIdx.x * 64;
    {
        const float4* Xv = (const float4*)(X + (size_t)nb * 128);
        float4* sv = (float4*)xs;
        for (int i = t; i < 64 * 32; i += 256) {
            int node = i >> 5;
            float4 v = make_float4(0.f, 0.f, 0.f, 0.f);
            if (nb + node < n) v = Xv[i];
            sv[i] = v;
        }
    }
    __syncthreads();
    const int colb = (t & 31) * 4;
    const int nodeb = (t >> 5) * 8;
    float acc[8][4];
#pragma unroll
    for (int i = 0; i < 8; i++) { acc[i][0] = acc[i][1] = acc[i][2] = acc[i][3] = 0.f; }

    for (int k4 = 0; k4 < 128; k4 += 4) {
        float4 w0 = *(const float4*)(W + (k4 + 0) * 128 + colb);
        float4 w1 = *(const float4*)(W + (k4 + 1) * 128 + colb);
        float4 w2 = *(const float4*)(W + (k4 + 2) * 128 + colb);
        float4 w3 = *(const float4*)(W + (k4 + 3) * 128 + colb);
#pragma unroll
        for (int i = 0; i < 8; i++) {
            float4 xv = *(const float4*)&xs[(nodeb + i) * 128 + k4];
            acc[i][0] += xv.x * w0.x + xv.y * w1.x + xv.z * w2.x + xv.w * w3.x;
            acc[i][1] += xv.x * w0.y + xv.y * w1.y + xv.z * w2.y + xv.w * w3.y;
            acc[i][2] += xv.x * w0.z + xv.y * w1.z + xv.z * w2.z + xv.w * w3.z;
            acc[i][3] += xv.x * w0.w + xv.y * w1.w + xv.z * w2.w + xv.w * w3.w;
        }
    }
#pragma unroll
    for (int i = 0; i < 8; i++) {
        int node = nb + nodeb + i;
        if (node < n)
            *(float4*)(Y + (size_t)node * 128 + colb) =
                make_float4(acc[i][0], acc[i][1], acc[i][2], acc[i][3]);
    }
}

// ---------------- CSR build ----------------------------------------------------
__global__ __launch_bounds__(256) void set_ones(int* __restrict__ cnt, int n) {
    int i = blockIdx.x * 256 + threadIdx.x;
    if (i < n) cnt[i] = 1;   // self loop
}

__global__ __launch_bounds__(256) void count_edges(const int* __restrict__ dsts,
                                                   int E0, int* __restrict__ cnt) {
    int e = blockIdx.x * 256 + threadIdx.x;
    if (e < E0) atomicAdd(&cnt[dsts[e]], 1);
}

// pass 1: per-1024-chunk exclusive scan (256 thr x 4 elems), chunk totals -> bsum
__global__ __launch_bounds__(256) void scan1(const int* __restrict__ cnt,
                                             int* __restrict__ off,
                                             int* __restrict__ bsum, int n) {
    __shared__ int lds[256];
    const int t = threadIdx.x;
    const int idx = blockIdx.x * 1024 + t * 4;
    int a0 = idx + 0 < n ? cnt[idx + 0] : 0;
    int a1 = idx + 1 < n ? cnt[idx + 1] : 0;
    int a2 = idx + 2 < n ? cnt[idx + 2] : 0;
    int a3 = idx + 3 < n ? cnt[idx + 3] : 0;
    int tsum = a0 + a1 + a2 + a3;
    lds[t] = tsum;
    __syncthreads();
    for (int d = 1; d < 256; d <<= 1) {
        int x = (t >= d) ? lds[t - d] : 0;
        __syncthreads();
        lds[t] += x;
        __syncthreads();
    }
    int excl = lds[t] - tsum;
    if (idx + 0 < n) off[idx + 0] = excl;
    if (idx + 1 < n) off[idx + 1] = excl + a0;
    if (idx + 2 < n) off[idx + 2] = excl + a0 + a1;
    if (idx + 3 < n) off[idx + 3] = excl + a0 + a1 + a2;
    if (t == 255) bsum[blockIdx.x] = lds[255];
}

// pass 2: single-wave exclusive scan of chunk sums (any nb, 64-wide chunks)
__global__ __launch_bounds__(64) void scan2(int* __restrict__ bsum, int nb,
                                            int* __restrict__ off_total) {
    const int t = threadIdx.x;
    int carry = 0;
    for (int base = 0; base < nb; base += 64) {
        int v = (base + t < nb) ? bsum[base + t] : 0;
        const int orig = v;
        for (int d = 1; d < 64; d <<= 1) {
            int u = __shfl_up(v, d, 64);
            if (t >= d) v += u;
        }
        if (base + t < nb) bsum[base + t] = v - orig + carry;
        carry += __shfl(v, 63, 64);
    }
    if (t == 0) *off_total = carry;
}

// pass 3: add chunk bases; also init cursor copy
__global__ __launch_bounds__(256) void scan3(int* __restrict__ off,
                                             int* __restrict__ cursor,
                                             const int* __restrict__ bsum, int n) {
    int i = blockIdx.x * 256 + threadIdx.x;
    if (i < n) {
        int v = off[i] + bsum[i >> 10];
        off[i] = v;
        cursor[i] = v;
    }
}

// scatter src ids into adjacency; gid in [0,E0) real edges, [E0,E0+n) self loops
__global__ __launch_bounds__(256) void scatter_edges(const int* __restrict__ srcs,
                                                     const int* __restrict__ dsts,
                                                     int E0, int n,
                                                     int* __restrict__ cursor,
                                                     int* __restrict__ adj) {
    int gid = blockIdx.x * 256 + threadIdx.x;
    if (gid >= E0 + n) return;
    int sN, dN;
    if (gid < E0) { sN = srcs[gid]; dN = dsts[gid]; }
    else          { sN = gid - E0;  dN = sN; }
    int pos = atomicAdd(&cursor[dN], 1);
    adj[pos] = sN;
}

// ---------------- fused gather: logits + online softmax + aggregate + bias+relu
// One wave per destination node; lane = head*8 + chanpair. Unrolled x4 for MLP.
__global__ __launch_bounds__(256) void node_gather(const float* __restrict__ xl,
                                                   const float* __restrict__ xr,
                                                   const float* __restrict__ att,
                                                   const int* __restrict__ adj,
                                                   const int* __restrict__ off,
                                                   const float* __restrict__ bias,
                                                   float* __restrict__ out, int n) {
    const int t = threadIdx.x;
    const int lane = t & 63;
    const int node = blockIdx.x * 4 + (t >> 6);
    if (node >= n) return;
    const int h = lane >> 3;           // 0..7
    const int col = h * 16 + (lane & 7) * 2;
    const float a0 = att[col], a1 = att[col + 1];
    const float2 r = *(const float2*)(xr + (size_t)node * FDIM + col);
    float mx = -1e30f, s = 0.f, acc0 = 0.f, acc1 = 0.f;
    int j = off[node];
    const int end = off[node + 1];

    for (; j + 4 <= end; j += 4) {
        const int s0 = adj[j], s1 = adj[j + 1], s2 = adj[j + 2], s3 = adj[j + 3];
        const float2 l0 = *(const float2*)(xl + (size_t)s0 * FDIM + col);
        const float2 l1 = *(const float2*)(xl + (size_t)s1 * FDIM + col);
        const float2 l2 = *(const float2*)(xl + (size_t)s2 * FDIM + col);
        const float2 l3 = *(const float2*)(xl + (size_t)s3 * FDIM + col);
        float v, p0, p1, p2, p3;
        v = l0.x + r.x; v = v > 0.f ? v : NEG_SLOPE * v; p0  = v * a0;
        v = l0.y + r.y; v = v > 0.f ? v : NEG_SLOPE * v; p0 += v * a1;
        v = l1.x + r.x; v = v > 0.f ? v : NEG_SLOPE * v; p1  = v * a0;
        v = l1.y + r.y; v = v > 0.f ? v : NEG_SLOPE * v; p1 += v * a1;
        v = l2.x + r.x; v = v > 0.f ? v : NEG_SLOPE * v; p2  = v * a0;
        v = l2.y + r.y; v = v > 0.f ? v : NEG_SLOPE * v; p2 += v * a1;
        v = l3.x + r.x; v = v > 0.f ? v : NEG_SLOPE * v; p3  = v * a0;
        v = l3.y + r.y; v = v > 0.f ? v : NEG_SLOPE * v; p3 += v * a1;
        p0 += __shfl_xor(p0, 1, 64); p0 += __shfl_xor(p0, 2, 64); p0 += __shfl_xor(p0, 4, 64);
        p1 += __shfl_xor(p1, 1, 64); p1 += __shfl_xor(p1, 2, 64); p1 += __shfl_xor(p1, 4, 64);
        p2 += __shfl_xor(p2, 1, 64); p2 += __shfl_xor(p2, 2, 64); p2 += __shfl_xor(p2, 4, 64);
        p3 += __shfl_xor(p3, 1, 64); p3 += __shfl_xor(p3, 2, 64); p3 += __shfl_xor(p3, 4, 64);
        const float nm = fmaxf(mx, fmaxf(fmaxf(p0, p1), fmaxf(p2, p3)));
        const float sc = __expf(mx - nm);
        const float e0 = __expf(p0 - nm), e1 = __expf(p1 - nm);
        const float e2 = __expf(p2 - nm), e3 = __expf(p3 - nm);
        s    = s    * sc + ((e0 + e1) + (e2 + e3));
        acc0 = acc0 * sc + ((e0 * l0.x + e1 * l1.x) + (e2 * l2.x + e3 * l3.x));
        acc1 = acc1 * sc + ((e0 * l0.y + e1 * l1.y) + (e2 * l2.y + e3 * l3.y));
        mx = nm;
    }
    for (; j < end; j++) {
        const int src = adj[j];
        const float2 l = *(const float2*)(xl + (size_t)src * FDIM + col);
        float v0 = l.x + r.x; v0 = v0 > 0.f ? v0 : NEG_SLOPE * v0;
        float v1 = l.y + r.y; v1 = v1 > 0.f ? v1 : NEG_SLOPE * v1;
        float p = v0 * a0 + v1 * a1;
        p += __shfl_xor(p, 1, 64);
        p += __shfl_xor(p, 2, 64);
        p += __shfl_xor(p, 4, 64);
        const float nm = fmaxf(mx, p);
        const float sc = __expf(mx - nm);
        const float a = __expf(p - nm);
        s = s * sc + a;
        acc0 = acc0 * sc + a * l.x;
        acc1 = acc1 * sc + a * l.y;
        mx = nm;
    }
    const float inv = 1.f / (s + 1e-16f);
    float o0 = acc0 * inv + bias[col];
    float o1 = acc1 * inv + bias[col + 1];
    out[(size_t)node * FDIM + col]     = o0 > 0.f ? o0 : 0.f;
    out[(size_t)node * FDIM + col + 1] = o1 > 0.f ? o1 : 0.f;
}

// ---------------- final linear (128->16) + log_softmax -------------------------
__global__ __launch_bounds__(256) void final_head(const float* __restrict__ H,
                                                  const float* __restrict__ Wlin,
                                                  const float* __restrict__ blin,
                                                  float* __restrict__ out, int n) {
    __shared__ float Ws[128 * NCLS];   // 8 KB
    const int t = threadIdx.x;
    for (int i = t; i < 128 * NCLS; i += 256) Ws[i] = Wlin[i];
    __syncthreads();
    const int cls = t & 15;
    const int node = blockIdx.x * 16 + (t >> 4);
    if (node >= n) return;
    const float* row = H + (size_t)node * FDIM;
    float acc = blin[cls];
#pragma unroll 4
    for (int k = 0; k < 128; k++) acc += row[k] * Ws[k * NCLS + cls];
    float mx = acc;
#pragma unroll
    for (int off = 8; off > 0; off >>= 1) mx = fmaxf(mx, __shfl_xor(mx, off, 16));
    float ex = __expf(acc - mx);
    float sm = ex;
#pragma unroll
    for (int off = 8; off > 0; off >>= 1) sm += __shfl_xor(sm, off, 16);
    out[(size_t)node * NCLS + cls] = acc - mx - __logf(sm);
}

// ==============================================================================
extern "C" void kernel_launch(void* const* d_in, const int* in_sizes, int n_in,
                              void* d_out, int out_size, void* d_ws, size_t ws_size,
                              hipStream_t stream) {
    const float* x    = (const float*)d_in[0];
    const int*   edge = (const int*)d_in[1];
    const float* Wl1  = (const float*)d_in[2];
    const float* Wr1  = (const float*)d_in[3];
    const float* att1 = (const float*)d_in[4];
    const float* b1   = (const float*)d_in[5];
    const float* Wl2  = (const float*)d_in[6];
    const float* Wr2  = (const float*)d_in[7];
    const float* att2 = (const float*)d_in[8];
    const float* b2   = (const float*)d_in[9];
    const float* Wlin = (const float*)d_in[10];
    const float* blin = (const float*)d_in[11];

    const int N = in_sizes[0] / FDIM;        // 50000
    const int E0 = in_sizes[1] / 2;          // 1600000
    const int Etot = E0 + N;
    const int* srcs = edge;
    const int* dsts = edge + E0;

    float* A   = (float*)d_ws;               // xl   N*128
    float* B   = A + (size_t)N * FDIM;       // xr   N*128
    float* C   = B + (size_t)N * FDIM;       // conv output N*128
    int* cnt    = (int*)(C + (size_t)N * FDIM);
    int* off    = cnt + N;                   // N+1
    int* cursor = off + N + 1;               // N
    int* bsum   = cursor + N;                // scan chunk sums
    int* adj    = bsum + ((N + 1023) / 1024) + 64;  // Etot

    const int gemm_blocks = (N + 63) / 64;
    const int node_blocks = (N + 3) / 4;
    const int nchunks = (N + 1023) / 1024;

    // ---------------- CSR build (shared by both layers) ----------------
    set_ones<<<(N + 255) / 256, 256, 0, stream>>>(cnt, N);
    count_edges<<<(E0 + 255) / 256, 256, 0, stream>>>(dsts, E0, cnt);
    scan1<<<nchunks, 256, 0, stream>>>(cnt, off, bsum, N);
    scan2<<<1, 64, 0, stream>>>(bsum, nchunks, off + N);
    scan3<<<(N + 255) / 256, 256, 0, stream>>>(off, cursor, bsum, N);
    scatter_edges<<<(Etot + 255) / 256, 256, 0, stream>>>(srcs, dsts, E0, N, cursor, adj);

    // ---------------- layer 1 ----------------
    gemm128_dual<<<dim3(gemm_blocks, 2), 256, 0, stream>>>(x, Wl1, Wr1, A, B, N);
    node_gather<<<node_blocks, 256, 0, stream>>>(A, B, att1, adj, off, b1, C, N);

    // ---------------- layer 2 ----------------
    gemm128_dual<<<dim3(gemm_blocks, 2), 256, 0, stream>>>(C, Wl2, Wr2, A, B, N);
    node_gather<<<node_blocks, 256, 0, stream>>>(A, B, att2, adj, off, b2, C, N);

    // ---------------- head ----------------
    final_head<<<(N + 15) / 16, 256, 0, stream>>>(C, Wlin, blin, (float*)d_out, N);
}

// Round 4
// 519.941 us; speedup vs baseline: 47.1025x; 1.2470x over previous
//
#include <hip/hip_runtime.h>

#define HEADS 8
#define FDIM 128          // HEADS*16 = feature width of both conv layers
#define NCLS 16
#define NEG_SLOPE 0.2f

// ---------------- count + rank: rank[e] = arrival order within its dst ---------
__global__ __launch_bounds__(256) void count_rank(const int* __restrict__ dsts,
                                                  int E0, int* __restrict__ cnt,
                                                  int* __restrict__ rank) {
    int e = blockIdx.x * 256 + threadIdx.x;
    if (e < E0) rank[e] = atomicAdd(&cnt[dsts[e]], 1);
}

// pass 1: per-1024-chunk exclusive scan (256 thr x 4 elems), chunk totals -> bsum
__global__ __launch_bounds__(256) void scan1(const int* __restrict__ cnt,
                                             int* __restrict__ off,
                                             int* __restrict__ bsum, int n) {
    __shared__ int lds[256];
    const int t = threadIdx.x;
    const int idx = blockIdx.x * 1024 + t * 4;
    int a0 = idx + 0 < n ? cnt[idx + 0] : 0;
    int a1 = idx + 1 < n ? cnt[idx + 1] : 0;
    int a2 = idx + 2 < n ? cnt[idx + 2] : 0;
    int a3 = idx + 3 < n ? cnt[idx + 3] : 0;
    int tsum = a0 + a1 + a2 + a3;
    lds[t] = tsum;
    __syncthreads();
    for (int d = 1; d < 256; d <<= 1) {
        int x = (t >= d) ? lds[t - d] : 0;
        __syncthreads();
        lds[t] += x;
        __syncthreads();
    }
    int excl = lds[t] - tsum;
    if (idx + 0 < n) off[idx + 0] = excl;
    if (idx + 1 < n) off[idx + 1] = excl + a0;
    if (idx + 2 < n) off[idx + 2] = excl + a0 + a1;
    if (idx + 3 < n) off[idx + 3] = excl + a0 + a1 + a2;
    if (t == 255) bsum[blockIdx.x] = lds[255];
}

// pass 2: single-wave exclusive scan of chunk sums
__global__ __launch_bounds__(64) void scan2(int* __restrict__ bsum, int nb,
                                            int* __restrict__ off_total) {
    const int t = threadIdx.x;
    int carry = 0;
    for (int base = 0; base < nb; base += 64) {
        int v = (base + t < nb) ? bsum[base + t] : 0;
        const int orig = v;
        for (int d = 1; d < 64; d <<= 1) {
            int u = __shfl_up(v, d, 64);
            if (t >= d) v += u;
        }
        if (base + t < nb) bsum[base + t] = v - orig + carry;
        carry += __shfl(v, 63, 64);
    }
    if (t == 0) *off_total = carry;
}

// pass 3: add chunk bases
__global__ __launch_bounds__(256) void scan3(int* __restrict__ off,
                                             const int* __restrict__ bsum, int n) {
    int i = blockIdx.x * 256 + threadIdx.x;
    if (i < n) off[i] += bsum[i >> 10];
}

// ---------------- fused: dual GEMM (y=0,1) + atomic-free scatter (y=2) ---------
// GEMM: Y[n,128] = X[n,128] @ W[128,128]; 64-node LDS tile, 8x4 per thread.
// Scatter: adj[off[dst]+rank[e]] = src  (pure stores, overlapped with GEMM).
__global__ __launch_bounds__(256) void gemm_scatter(const float* __restrict__ X,
                                                    const float* __restrict__ W0,
                                                    const float* __restrict__ W1,
                                                    float* __restrict__ Y0,
                                                    float* __restrict__ Y1, int n,
                                                    const int* __restrict__ srcs,
                                                    const int* __restrict__ dsts,
                                                    const int* __restrict__ rank,
                                                    const int* __restrict__ off,
                                                    int* __restrict__ adj, int E0) {
    __shared__ float xs[64 * 128];   // 32 KB
    const int t = threadIdx.x;
    if (blockIdx.y == 2) {
        int i = blockIdx.x * 256 + t;
        const int stride = gridDim.x * 256;
        for (; i < E0; i += stride)
            adj[off[dsts[i]] + rank[i]] = srcs[i];
        return;
    }
    const float* W = blockIdx.y ? W1 : W0;
    float* Y = blockIdx.y ? Y1 : Y0;
    const int nb = blockIdx.x * 64;
    {
        const float4* Xv = (const float4*)(X + (size_t)nb * 128);
        float4* sv = (float4*)xs;
        for (int i = t; i < 64 * 32; i += 256) {
            int node = i >> 5;
            float4 v = make_float4(0.f, 0.f, 0.f, 0.f);
            if (nb + node < n) v = Xv[i];
            sv[i] = v;
        }
    }
    __syncthreads();
    const int colb = (t & 31) * 4;
    const int nodeb = (t >> 5) * 8;
    float acc[8][4];
#pragma unroll
    for (int i = 0; i < 8; i++) { acc[i][0] = acc[i][1] = acc[i][2] = acc[i][3] = 0.f; }

    for (int k4 = 0; k4 < 128; k4 += 4) {
        float4 w0 = *(const float4*)(W + (k4 + 0) * 128 + colb);
        float4 w1 = *(const float4*)(W + (k4 + 1) * 128 + colb);
        float4 w2 = *(const float4*)(W + (k4 + 2) * 128 + colb);
        float4 w3 = *(const float4*)(W + (k4 + 3) * 128 + colb);
#pragma unroll
        for (int i = 0; i < 8; i++) {
            float4 xv = *(const float4*)&xs[(nodeb + i) * 128 + k4];
            acc[i][0] += xv.x * w0.x + xv.y * w1.x + xv.z * w2.x + xv.w * w3.x;
            acc[i][1] += xv.x * w0.y + xv.y * w1.y + xv.z * w2.y + xv.w * w3.y;
            acc[i][2] += xv.x * w0.z + xv.y * w1.z + xv.z * w2.z + xv.w * w3.z;
            acc[i][3] += xv.x * w0.w + xv.y * w1.w + xv.z * w2.w + xv.w * w3.w;
        }
    }
#pragma unroll
    for (int i = 0; i < 8; i++) {
        int node = nb + nodeb + i;
        if (node < n)
            *(float4*)(Y + (size_t)node * 128 + colb) =
                make_float4(acc[i][0], acc[i][1], acc[i][2], acc[i][3]);
    }
}

// ---------------- fused gather: self-loop + online softmax + aggregate + bias
// + relu; optional fused final linear (128->16) + log_softmax when headW != 0.
// One wave per destination node; lane = head*8 + chanpair.
__global__ __launch_bounds__(256) void node_gather(const float* __restrict__ xl,
                                                   const float* __restrict__ xr,
                                                   const float* __restrict__ att,
                                                   const int* __restrict__ adj,
                                                   const int* __restrict__ off,
                                                   const float* __restrict__ bias,
                                                   float* __restrict__ outC,
                                                   const float* __restrict__ headW,
                                                   const float* __restrict__ headB,
                                                   float* __restrict__ outH, int n) {
    __shared__ float WsL[FDIM * NCLS];   // 8 KB
    __shared__ float stage[4][FDIM];     // 2 KB
    const int t = threadIdx.x;
    if (headW) {   // uniform branch across the grid
        for (int i = t; i < FDIM * NCLS; i += 256) WsL[i] = headW[i];
        __syncthreads();
    }
    const int lane = t & 63;
    const int w = t >> 6;
    const int node = blockIdx.x * 4 + w;
    if (node >= n) return;
    const int h = lane >> 3;           // 0..7
    const int col = h * 16 + (lane & 7) * 2;
    const float a0 = att[col], a1 = att[col + 1];
    const float2 r = *(const float2*)(xr + (size_t)node * FDIM + col);

    // self-loop edge (src == node) seeds the online softmax
    const float2 lself = *(const float2*)(xl + (size_t)node * FDIM + col);
    float mx, s, acc0, acc1;
    {
        float v0 = lself.x + r.x; v0 = v0 > 0.f ? v0 : NEG_SLOPE * v0;
        float v1 = lself.y + r.y; v1 = v1 > 0.f ? v1 : NEG_SLOPE * v1;
        float p = v0 * a0 + v1 * a1;
        p += __shfl_xor(p, 1, 64);
        p += __shfl_xor(p, 2, 64);
        p += __shfl_xor(p, 4, 64);
        mx = p; s = 1.f; acc0 = lself.x; acc1 = lself.y;
    }

    int j = off[node];
    const int end = off[node + 1];
    for (; j + 4 <= end; j += 4) {
        const int s0 = adj[j], s1 = adj[j + 1], s2 = adj[j + 2], s3 = adj[j + 3];
        const float2 l0 = *(const float2*)(xl + (size_t)s0 * FDIM + col);
        const float2 l1 = *(const float2*)(xl + (size_t)s1 * FDIM + col);
        const float2 l2 = *(const float2*)(xl + (size_t)s2 * FDIM + col);
        const float2 l3 = *(const float2*)(xl + (size_t)s3 * FDIM + col);
        float v, p0, p1, p2, p3;
        v = l0.x + r.x; v = v > 0.f ? v : NEG_SLOPE * v; p0  = v * a0;
        v = l0.y + r.y; v = v > 0.f ? v : NEG_SLOPE * v; p0 += v * a1;
        v = l1.x + r.x; v = v > 0.f ? v : NEG_SLOPE * v; p1  = v * a0;
        v = l1.y + r.y; v = v > 0.f ? v : NEG_SLOPE * v; p1 += v * a1;
        v = l2.x + r.x; v = v > 0.f ? v : NEG_SLOPE * v; p2  = v * a0;
        v = l2.y + r.y; v = v > 0.f ? v : NEG_SLOPE * v; p2 += v * a1;
        v = l3.x + r.x; v = v > 0.f ? v : NEG_SLOPE * v; p3  = v * a0;
        v = l3.y + r.y; v = v > 0.f ? v : NEG_SLOPE * v; p3 += v * a1;
        p0 += __shfl_xor(p0, 1, 64); p0 += __shfl_xor(p0, 2, 64); p0 += __shfl_xor(p0, 4, 64);
        p1 += __shfl_xor(p1, 1, 64); p1 += __shfl_xor(p1, 2, 64); p1 += __shfl_xor(p1, 4, 64);
        p2 += __shfl_xor(p2, 1, 64); p2 += __shfl_xor(p2, 2, 64); p2 += __shfl_xor(p2, 4, 64);
        p3 += __shfl_xor(p3, 1, 64); p3 += __shfl_xor(p3, 2, 64); p3 += __shfl_xor(p3, 4, 64);
        const float nm = fmaxf(mx, fmaxf(fmaxf(p0, p1), fmaxf(p2, p3)));
        const float sc = __expf(mx - nm);
        const float e0 = __expf(p0 - nm), e1 = __expf(p1 - nm);
        const float e2 = __expf(p2 - nm), e3 = __expf(p3 - nm);
        s    = s    * sc + ((e0 + e1) + (e2 + e3));
        acc0 = acc0 * sc + ((e0 * l0.x + e1 * l1.x) + (e2 * l2.x + e3 * l3.x));
        acc1 = acc1 * sc + ((e0 * l0.y + e1 * l1.y) + (e2 * l2.y + e3 * l3.y));
        mx = nm;
    }
    for (; j < end; j++) {
        const int src = adj[j];
        const float2 l = *(const float2*)(xl + (size_t)src * FDIM + col);
        float v0 = l.x + r.x; v0 = v0 > 0.f ? v0 : NEG_SLOPE * v0;
        float v1 = l.y + r.y; v1 = v1 > 0.f ? v1 : NEG_SLOPE * v1;
        float p = v0 * a0 + v1 * a1;
        p += __shfl_xor(p, 1, 64);
        p += __shfl_xor(p, 2, 64);
        p += __shfl_xor(p, 4, 64);
        const float nm = fmaxf(mx, p);
        const float sc = __expf(mx - nm);
        const float a = __expf(p - nm);
        s = s * sc + a;
        acc0 = acc0 * sc + a * l.x;
        acc1 = acc1 * sc + a * l.y;
        mx = nm;
    }
    const float inv = 1.f / (s + 1e-16f);
    float o0 = acc0 * inv + bias[col];
    float o1 = acc1 * inv + bias[col + 1];
    o0 = o0 > 0.f ? o0 : 0.f;
    o1 = o1 > 0.f ? o1 : 0.f;

    if (!headW) {
        outC[(size_t)node * FDIM + col]     = o0;
        outC[(size_t)node * FDIM + col + 1] = o1;
        return;
    }
    // ---- fused head: wave-local LDS transpose, 128->16 dot, log_softmax ----
    stage[w][col]     = o0;
    stage[w][col + 1] = o1;
    const int cls = lane & 15;
    const int q = lane >> 4;          // quarter of the k-range
    float acc = 0.f;
#pragma unroll
    for (int k = 0; k < 32; k++)
        acc += stage[w][q * 32 + k] * WsL[(q * 32 + k) * NCLS + cls];
    acc += __shfl_xor(acc, 16, 64);
    acc += __shfl_xor(acc, 32, 64);
    acc += headB[cls];
    float m2 = acc;
    m2 = fmaxf(m2, __shfl_xor(m2, 8, 64));
    m2 = fmaxf(m2, __shfl_xor(m2, 4, 64));
    m2 = fmaxf(m2, __shfl_xor(m2, 2, 64));
    m2 = fmaxf(m2, __shfl_xor(m2, 1, 64));
    float sm = __expf(acc - m2);
    sm += __shfl_xor(sm, 8, 64);
    sm += __shfl_xor(sm, 4, 64);
    sm += __shfl_xor(sm, 2, 64);
    sm += __shfl_xor(sm, 1, 64);
    if (lane < 16)
        outH[(size_t)node * NCLS + cls] = acc - m2 - __logf(sm);
}

// ==============================================================================
extern "C" void kernel_launch(void* const* d_in, const int* in_sizes, int n_in,
                              void* d_out, int out_size, void* d_ws, size_t ws_size,
                              hipStream_t stream) {
    const float* x    = (const float*)d_in[0];
    const int*   edge = (const int*)d_in[1];
    const float* Wl1  = (const float*)d_in[2];
    const float* Wr1  = (const float*)d_in[3];
    const float* att1 = (const float*)d_in[4];
    const float* b1   = (const float*)d_in[5];
    const float* Wl2  = (const float*)d_in[6];
    const float* Wr2  = (const float*)d_in[7];
    const float* att2 = (const float*)d_in[8];
    const float* b2   = (const float*)d_in[9];
    const float* Wlin = (const float*)d_in[10];
    const float* blin = (const float*)d_in[11];

    const int N = in_sizes[0] / FDIM;        // 50000
    const int E0 = in_sizes[1] / 2;          // 1600000
    const int* srcs = edge;
    const int* dsts = edge + E0;

    float* A   = (float*)d_ws;               // xl   N*128
    float* B   = A + (size_t)N * FDIM;       // xr   N*128
    float* C   = B + (size_t)N * FDIM;       // conv1 output N*128
    int* cnt   = (int*)(C + (size_t)N * FDIM);
    int* off   = cnt + N;                    // N+1
    int* bsum  = off + N + 1;                // scan chunk sums (+pad)
    int* rank  = bsum + ((N + 1023) / 1024) + 64;   // E0
    int* adj   = rank + E0;                  // E0

    const int gemm_blocks = (N + 63) / 64;
    const int node_blocks = (N + 3) / 4;
    const int nchunks = (N + 1023) / 1024;

    // ---------------- CSR build (shared by both layers) ----------------
    hipMemsetAsync(cnt, 0, (size_t)N * sizeof(int), stream);
    count_rank<<<(E0 + 255) / 256, 256, 0, stream>>>(dsts, E0, cnt, rank);
    scan1<<<nchunks, 256, 0, stream>>>(cnt, off, bsum, N);
    scan2<<<1, 64, 0, stream>>>(bsum, nchunks, off + N);
    scan3<<<(N + 255) / 256, 256, 0, stream>>>(off, bsum, N);

    // ---------------- layer 1 (GEMMs overlapped with edge scatter) -------
    gemm_scatter<<<dim3(gemm_blocks, 3), 256, 0, stream>>>(
        x, Wl1, Wr1, A, B, N, srcs, dsts, rank, off, adj, E0);
    node_gather<<<node_blocks, 256, 0, stream>>>(A, B, att1, adj, off, b1, C,
                                                 nullptr, nullptr, nullptr, N);

    // ---------------- layer 2 ----------------
    gemm_scatter<<<dim3(gemm_blocks, 2), 256, 0, stream>>>(
        C, Wl2, Wr2, A, B, N, nullptr, nullptr, nullptr, nullptr, nullptr, 0);
    node_gather<<<node_blocks, 256, 0, stream>>>(A, B, att2, adj, off, b2,
                                                 nullptr, Wlin, blin,
                                                 (float*)d_out, N);
}